// Round 7
// baseline (326.793 us; speedup 1.0000x reference)
//
#include <hip/hip_runtime.h>
#include <hip/hip_fp16.h>

// ProtoNet distance matrix: out[n,k] = (alpha+1e-16)^2 * (||x_n||^2 + ||p_k||^2 - 2 x_n.p_k)
// x: [16384,1024] f32, p: [2048,1024] f32, alpha: [1] f32, out: [16384,2048] f32.
//
// v5: TLP-first design. Findings r3-r6: all intra-block schedules tie (~690 TF)
// because 256^2 (acc=128 VGPR) caps at 1 block/CU and lockstep barriers
// serialize LDS+MFMA. Fix: 128^2 tile (acc=64 VGPR, ~175 total, launch_bounds
// (256,3) -> 3 blocks/CU TLP) + B read DIRECT from global (4MB, L2/L3-resident;
// m169: don't stage cache-fit data) into regs, prefetched 1 tile ahead.
// LDS holds only A: 2 x 16KB double buffer, XOR-swizzled via pre-swizzled
// global source (dest linear: uniform base + lane*16).

#define N_ROWS 16384
#define K_PROTO 2048
#define DIM 1024

#define BM 128
#define BN 128
#define BK 64
#define NT (DIM / BK)   // 16 K-tiles

typedef _Float16 half8 __attribute__((ext_vector_type(8)));
typedef float f32x4 __attribute__((ext_vector_type(4)));

__device__ __forceinline__ void async_copy16(void* lds_dst, const void* g_src) {
    __builtin_amdgcn_global_load_lds(
        (const __attribute__((address_space(1))) void*)g_src,
        (__attribute__((address_space(3))) void*)lds_dst,
        16, 0, 0);
}

// ---------------- Pass 1: convert + row sum-of-squares (unchanged, verified) ----------------
__global__ __launch_bounds__(256) void convert_kernel(
    const float* __restrict__ x, const float* __restrict__ p,
    __half* __restrict__ xh, __half* __restrict__ ph,
    float* __restrict__ xsq, float* __restrict__ psq)
{
    int row = blockIdx.x;
    const float* src;
    __half* dst;
    float* sq;
    if (row < N_ROWS) {
        src = x + (size_t)row * DIM;
        dst = xh + (size_t)row * DIM;
        sq = xsq + row;
    } else {
        int r = row - N_ROWS;
        src = p + (size_t)r * DIM;
        dst = ph + (size_t)r * DIM;
        sq = psq + r;
    }
    int t = threadIdx.x;  // 256 threads x 4 floats = 1024
    float4 v = reinterpret_cast<const float4*>(src)[t];
    float s = v.x * v.x + v.y * v.y + v.z * v.z + v.w * v.w;

    union { __half2 h[2]; uint2 u; } pk;
    pk.h[0] = __floats2half2_rn(v.x, v.y);
    pk.h[1] = __floats2half2_rn(v.z, v.w);
    reinterpret_cast<uint2*>(dst)[t] = pk.u;

    #pragma unroll
    for (int off = 32; off > 0; off >>= 1) s += __shfl_down(s, off);
    __shared__ float red[4];
    if ((t & 63) == 0) red[t >> 6] = s;
    __syncthreads();
    if (t == 0) sq[0] = red[0] + red[1] + red[2] + red[3];
}

// ---------------- Pass 2: 128^2 fp16 MFMA GEMM, A-in-LDS / B-direct ----------------
// grid = (16384/128)*(2048/128) = 128*16 = 2048 blocks, 256 threads (4 waves 2x2).
// LDS: 2 x A[128][64] f16 = 32KB total -> LDS allows 4+ blocks; VGPR (~175) -> 3.

#define LOADB(dst, kt)                                                            \
    do {                                                                          \
        _Pragma("unroll")                                                         \
        for (int n_ = 0; n_ < 4; ++n_) {                                          \
            const int row_ = bn * BN + wn * 64 + n_ * 16 + rr;                    \
            _Pragma("unroll")                                                     \
            for (int kk_ = 0; kk_ < 2; ++kk_)                                     \
                dst[n_][kk_] = *(const half8*)(ph + (size_t)row_ * DIM +          \
                                   (kt) * BK + (kk_ * 4 + lq) * 8);               \
        }                                                                         \
    } while (0)

#define COMPUTE(buf, Bc)                                                          \
    do {                                                                          \
        const char* Ab = lds[buf];                                                \
        _Pragma("unroll")                                                         \
        for (int kk_ = 0; kk_ < 2; ++kk_) {                                       \
            half8 af[4];                                                          \
            _Pragma("unroll")                                                     \
            for (int m_ = 0; m_ < 4; ++m_) {                                      \
                const int row_ = wm * 64 + m_ * 16 + rr;                          \
                af[m_] = *(const half8*)(Ab + row_ * 128 +                        \
                             (((kk_ * 4 + lq) ^ (row_ & 7)) << 4));               \
            }                                                                     \
            _Pragma("unroll")                                                     \
            for (int m_ = 0; m_ < 4; ++m_)                                        \
                _Pragma("unroll")                                                 \
                for (int n_ = 0; n_ < 4; ++n_)                                    \
                    acc[m_][n_] = __builtin_amdgcn_mfma_f32_16x16x32_f16(         \
                        af[m_], Bc[n_][kk_], acc[m_][n_], 0, 0, 0);               \
        }                                                                         \
    } while (0)

__global__ __launch_bounds__(256, 3) void gemm_kernel(
    const __half* __restrict__ xh, const __half* __restrict__ ph,
    const float* __restrict__ xsq, const float* __restrict__ psq,
    const float* __restrict__ alpha, float* __restrict__ out)
{
    __shared__ __align__(1024) char lds[2][BM * BK * 2];  // 2 x 16KB, A only

    const int tid = threadIdx.x;
    const int w = tid >> 6, lane = tid & 63;
    const int wm = w >> 1, wn = w & 1;        // 2x2 waves, wave tile 64x64
    const int rr = lane & 15, lq = lane >> 4;

    // XCD swizzle: grid 2048, 2048%8==0 -> bijective. XCD x gets bm in
    // [16x,16x+16) x all bn: A-slice 4MB + B 4MB working set per XCD.
    const int bid = blockIdx.x;
    const int swz = (bid & 7) * 256 + (bid >> 3);
    const int bm = swz >> 4, bn = swz & 15;

    f32x4 acc[4][4];
    #pragma unroll
    for (int m = 0; m < 4; ++m)
        #pragma unroll
        for (int n = 0; n < 4; ++n)
            acc[m][n] = (f32x4)0.0f;

    // stage A tile kt into lds[buf]: 16KB, 4 x 16B per thread; source
    // pre-swizzled so physical slot ps holds logical slot ps^(row&7).
    auto stage = [&](int buf, int kt) {
        char* base = lds[buf];
        #pragma unroll
        for (int i = 0; i < 4; ++i) {
            const int c = i * 256 + tid;       // 0..1023
            const int r = c >> 3;              // 0..127
            const int sl = (c & 7) ^ (r & 7);
            async_copy16(base + c * 16,
                         xh + (size_t)(bm * BM + r) * DIM + kt * BK + sl * 8);
        }
    };

    half8 BA[4][2], BB[4][2];

    stage(0, 0);
    LOADB(BA, 0);
    __syncthreads();   // drains vmcnt: A tile0 in LDS, B tile0 in regs

    for (int t = 0; t < NT; t += 2) {
        // even tile t: compute buf0/BA while staging t+1 into buf1/BB
        stage(1, t + 1);
        LOADB(BB, t + 1);
        COMPUTE(0, BA);
        __syncthreads();

        // odd tile t+1: compute buf1/BB while staging t+2 into buf0/BA
        if (t + 2 < NT) {
            stage(0, t + 2);
            LOADB(BA, t + 2);
        }
        COMPUTE(1, BB);
        __syncthreads();
    }

    // epilogue: out = scale * (xsq[row] + psq[col] - 2*cross)
    const float a = alpha[0] + 1e-16f;
    const float scale = a * a;
    const int row0 = bm * BM + wm * 64 + lq * 4;
    const int col0 = bn * BN + wn * 64 + rr;
    float4 xs4[4];
    #pragma unroll
    for (int m = 0; m < 4; ++m)
        xs4[m] = *reinterpret_cast<const float4*>(xsq + row0 + m * 16);
    #pragma unroll
    for (int n = 0; n < 4; ++n) {
        const int col = col0 + n * 16;
        const float pv = psq[col];
        #pragma unroll
        for (int m = 0; m < 4; ++m) {
            const int rbase = row0 + m * 16;
            #pragma unroll
            for (int r = 0; r < 4; ++r) {
                const float xv = (r == 0) ? xs4[m].x : (r == 1) ? xs4[m].y
                               : (r == 2) ? xs4[m].z : xs4[m].w;
                out[(size_t)(rbase + r) * K_PROTO + col] =
                    scale * (xv + pv - 2.0f * acc[m][n][r]);
            }
        }
    }
}

// ---------------- Fallback: direct fp32, no workspace (unchanged) ----------------
__global__ __launch_bounds__(256) void fallback_kernel(
    const float* __restrict__ x, const float* __restrict__ p,
    const float* __restrict__ alpha, float* __restrict__ out)
{
    __shared__ float xs[DIM];
    int n = blockIdx.x;
    int t = threadIdx.x;
    reinterpret_cast<float4*>(xs)[t] = reinterpret_cast<const float4*>(x + (size_t)n * DIM)[t];
    __syncthreads();
    const float a = alpha[0] + 1e-16f;
    const float scale = a * a;
    for (int j = 0; j < K_PROTO / 256; ++j) {
        int k = j * 256 + t;
        const float4* pr = reinterpret_cast<const float4*>(p + (size_t)k * DIM);
        float s = 0.0f;
        #pragma unroll 8
        for (int d4 = 0; d4 < DIM / 4; ++d4) {
            float4 pv = pr[d4];
            float dx = xs[d4 * 4 + 0] - pv.x;
            float dy = xs[d4 * 4 + 1] - pv.y;
            float dz = xs[d4 * 4 + 2] - pv.z;
            float dw = xs[d4 * 4 + 3] - pv.w;
            s += dx * dx + dy * dy + dz * dz + dw * dw;
        }
        out[(size_t)n * K_PROTO + k] = scale * s;
    }
}

extern "C" void kernel_launch(void* const* d_in, const int* in_sizes, int n_in,
                              void* d_out, int out_size, void* d_ws, size_t ws_size,
                              hipStream_t stream) {
    const float* x = (const float*)d_in[0];
    const float* p = (const float*)d_in[1];
    const float* alpha = (const float*)d_in[2];
    float* out = (float*)d_out;

    const size_t XH_BYTES = (size_t)N_ROWS * DIM * sizeof(__half);   // 32 MB
    const size_t PH_BYTES = (size_t)K_PROTO * DIM * sizeof(__half);  // 4 MB
    const size_t NEED = XH_BYTES + PH_BYTES +
                        (size_t)(N_ROWS + K_PROTO) * sizeof(float);

    if (ws_size < NEED) {
        fallback_kernel<<<dim3(N_ROWS), dim3(256), 0, stream>>>(x, p, alpha, out);
        return;
    }

    char* w = (char*)d_ws;
    __half* xh = (__half*)w;
    __half* ph = (__half*)(w + XH_BYTES);
    float* xsq = (float*)(w + XH_BYTES + PH_BYTES);
    float* psq = (float*)(w + XH_BYTES + PH_BYTES + N_ROWS * sizeof(float));

    convert_kernel<<<dim3(N_ROWS + K_PROTO), dim3(256), 0, stream>>>(
        x, p, xh, ph, xsq, psq);
    gemm_kernel<<<dim3((N_ROWS / BM) * (K_PROTO / BN)), dim3(256), 0, stream>>>(
        xh, ph, xsq, psq, alpha, out);
}